// Round 3
// baseline (204.465 us; speedup 1.0000x reference)
//
#include <hip/hip_runtime.h>
#include <math.h>

#define B_ 64
#define P_ 196
#define D_ 768
#define C_ 201
#define K_ 5
#define N_ (B_*P_)      // 12544
#define CK_ (C_*K_)     // 1005
#define NPAD 1024
#define NCLS 200
#define GAMMA_ 0.999f
#define INV_TEMP 5.0f
#define INV_EPS 20.0f
#define CAP2 256
#define MTILES 98       // 12544/128
#define ROWS_TOT (2*N_ + NPAD)   // 26112 rows for the norm pass

typedef short s16x8 __attribute__((ext_vector_type(8)));
typedef float f32x4 __attribute__((ext_vector_type(4)));
typedef unsigned short u16x4 __attribute__((ext_vector_type(4)));

typedef __attribute__((address_space(3))) void lds_void;
typedef __attribute__((address_space(1))) const void g_void;
#define GLD16(gp, lp) __builtin_amdgcn_global_load_lds((g_void*)(gp), (lds_void*)(lp), 16, 0, 0)

__device__ __forceinline__ unsigned short f2bf(float f) {
    unsigned int u = __float_as_uint(f);
    unsigned int r = (u + 0x7FFFu + ((u >> 16) & 1u)) >> 16;
    return (unsigned short)r;
}

// ---------------- norms + pre-scaled bf16 conversion: ONE WAVE PER ROW ----------------
// rows [0,N_) -> patch (scaled bf16), [N_,2N_) -> rawp (invR only), [2N_,2N_+NPAD) -> proto
__global__ __launch_bounds__(256) void norm_all_kernel(
        const float* __restrict__ patch, const float* __restrict__ rawp,
        const float* __restrict__ proto, float* __restrict__ invR,
        unsigned short* __restrict__ Abf, unsigned short* __restrict__ Bbf,
        int* __restrict__ cnt) {
    if (blockIdx.x == 0 && threadIdx.x < C_) cnt[threadIdx.x] = 0;
    int gw = blockIdx.x * 4 + (threadIdx.x >> 6);   // row index
    int lane = threadIdx.x & 63;
    const float* src; unsigned short* dst; int realR; int r; bool wantInv = false;
    if (gw < N_) { r = gw; src = patch; dst = Abf; realR = N_; }
    else if (gw < 2 * N_) { r = gw - N_; src = rawp; dst = nullptr; realR = N_; wantInv = true; }
    else { r = gw - 2 * N_; src = proto; dst = Bbf; realR = CK_; }
    unsigned short* brow = dst ? dst + (size_t)r * D_ : nullptr;
    if (r >= realR) {  // zero-pad proto rows
        u16x4 z = (u16x4)0;
        *(u16x4*)(brow + lane * 4)       = z;
        *(u16x4*)(brow + lane * 4 + 256) = z;
        *(u16x4*)(brow + lane * 4 + 512) = z;
        return;
    }
    const float4* row4 = (const float4*)(src + (size_t)r * D_);
    float4 v0 = row4[lane], v1 = row4[lane + 64], v2 = row4[lane + 128];
    float s = v0.x*v0.x + v0.y*v0.y + v0.z*v0.z + v0.w*v0.w
            + v1.x*v1.x + v1.y*v1.y + v1.z*v1.z + v1.w*v1.w
            + v2.x*v2.x + v2.y*v2.y + v2.z*v2.z + v2.w*v2.w;
#pragma unroll
    for (int o = 1; o < 64; o <<= 1) s += __shfl_xor(s, o, 64);
    float sc = 1.f / fmaxf(sqrtf(s), 1e-12f);
    if (brow) {
        u16x4 p0 = { f2bf(v0.x*sc), f2bf(v0.y*sc), f2bf(v0.z*sc), f2bf(v0.w*sc) };
        u16x4 p1 = { f2bf(v1.x*sc), f2bf(v1.y*sc), f2bf(v1.z*sc), f2bf(v1.w*sc) };
        u16x4 p2 = { f2bf(v2.x*sc), f2bf(v2.y*sc), f2bf(v2.z*sc), f2bf(v2.w*sc) };
        *(u16x4*)(brow + lane * 4)       = p0;
        *(u16x4*)(brow + lane * 4 + 256) = p1;
        *(u16x4*)(brow + lane * 4 + 512) = p2;
    } else if (wantInv && lane == 0) invR[r] = sc;
}

// ---------------- bf16 MFMA GEMM + fused per-tile image max ----------------
// R7: LDS-read-pipe was the wall (12 cyc/b128 x 8 per 16 MFMA => 15% MfmaUtil ceiling,
//     matching R6's counters). Changes:
//  (a) wave = 64x128 output (2 waves/block, 128 thr): 12 ds_read_b128 per 32 MFMA.
//  (b) chunk-XOR bank swizzle, GLD16-compatible (LDS dest linear; global SOURCE
//      pre-swizzled; ds_read applies same XOR): slot(row,ch) holds global ch^(row&3);
//      verified uniform 2-accesses/bank (minimum) across the wave.
//  (c) keep 3-buffer depth-2 counted vmcnt (now vmcnt(8): 8 GLD16/thread/stage)
//      + XCD chunked swizzle (FETCH 77->23MB confirmed in R5).
#define BM 128
#define BN 128
#define BKq 32
#define KITER (D_/BKq)   // 24
#define NBUF 3
__global__ __launch_bounds__(128, 2) void gemm_mfma_kernel(
    const unsigned short* __restrict__ Ab, const unsigned short* __restrict__ Bb,
    float* __restrict__ Cc,                 // logits [N_][CK_]
    float* __restrict__ part) {             // [MTILES][2][1024] per-(tile,slot) col max
    __shared__ short As[NBUF][BM * BKq];
    __shared__ short Bs[NBUF][BN * BKq];
    __shared__ float maxw[2][2][BN];
    int tid = threadIdx.x;                  // 0..127
    // XCD-aware chunked swizzle (bijective: 784 = 8*98)
    int bid = blockIdx.y * 8 + blockIdx.x;
    int swz = (bid & 7) * MTILES + (bid >> 3);
    int mtile = swz >> 3;
    int ntile = swz & 7;
    int mBase = mtile * BM;
    int nBase = ntile * BN;
    int w = tid >> 6;                       // 0..1
    int lane = tid & 63;
    int wm = w * 64;
    int mrow = lane & 15;
    int q = lane >> 4;
    int qx = (q ^ (mrow & 3)) * 8;          // swizzled k-chunk offset (shorts)

    f32x4 acc[4][8];
#pragma unroll
    for (int i = 0; i < 4; ++i)
#pragma unroll
        for (int j = 0; j < 8; ++j) acc[i][j] = (f32x4)(0.f);

    // staging: 4 A-slots + 4 B-slots per thread; slot s covers lds 16B-chunk c=tid+128*s
    const unsigned short* gA[4];
    const unsigned short* gB[4];
    int ldsOff[4];
#pragma unroll
    for (int s = 0; s < 4; ++s) {
        int c = tid + 128 * s;
        int row = c >> 2;
        int cx = (c & 3) ^ (row & 3);       // pre-swizzled global k-chunk
        gA[s] = Ab + (size_t)(mBase + row) * D_ + cx * 8;
        gB[s] = Bb + (size_t)(nBase + row) * D_ + cx * 8;
        ldsOff[s] = c * 8;                  // linear LDS dest (shorts)
    }

    auto stage = [&](int buf, int k0) {
#pragma unroll
        for (int s = 0; s < 4; ++s) GLD16(gA[s] + k0, &As[buf][ldsOff[s]]);
#pragma unroll
        for (int s = 0; s < 4; ++s) GLD16(gB[s] + k0, &Bs[buf][ldsOff[s]]);
    };

    stage(0, 0);
    stage(1, BKq);
    int aoff = (wm + mrow) * BKq + qx;
    int boff = mrow * BKq + qx;
    for (int u = 0; u < KITER; ++u) {
        if (u < KITER - 1) asm volatile("s_waitcnt vmcnt(8)" ::: "memory");
        else               asm volatile("s_waitcnt vmcnt(0)" ::: "memory");
        __builtin_amdgcn_s_barrier();
        __builtin_amdgcn_sched_barrier(0);
        if (u + 2 < KITER) stage((u + 2) % NBUF, (u + 2) * BKq);
        const short* Ac = As[u % NBUF];
        const short* Bc = Bs[u % NBUF];
        s16x8 a[4], b[8];
#pragma unroll
        for (int i = 0; i < 4; ++i)
            a[i] = *(const s16x8*)&Ac[aoff + 512 * i];
#pragma unroll
        for (int j = 0; j < 8; ++j)
            b[j] = *(const s16x8*)&Bc[boff + 512 * j];
#pragma unroll
        for (int i = 0; i < 4; ++i)
#pragma unroll
            for (int j = 0; j < 8; ++j)
                acc[i][j] = __builtin_amdgcn_mfma_f32_16x16x32_bf16(a[i], b[j], acc[i][j], 0, 0, 0);
    }

    // epilogue: plain stores (NT stores measured worse: WRITE_SIZE 55->96MB)
#pragma unroll
    for (int i = 0; i < 4; ++i) {
        int gm = mBase + wm + 16 * i + q * 4;
#pragma unroll
        for (int j = 0; j < 8; ++j) {
            int gn = nBase + 16 * j + mrow;
            if (gn < CK_) {
                Cc[(size_t)(gm + 0) * CK_ + gn] = acc[i][j][0];
                Cc[(size_t)(gm + 1) * CK_ + gn] = acc[i][j][1];
                Cc[(size_t)(gm + 2) * CK_ + gn] = acc[i][j][2];
                Cc[(size_t)(gm + 3) * CK_ + gn] = acc[i][j][3];
            }
        }
    }

    // fused max over this tile's rows, split by image boundary (tile spans <=2 images)
    int imgA = mBase / 196;
    int rstar = 196 * (imgA + 1);
#pragma unroll
    for (int j = 0; j < 8; ++j) {
        float m0 = -INFINITY, m1 = -INFINITY;
#pragma unroll
        for (int i = 0; i < 4; ++i) {
            int gm = mBase + wm + 16 * i + q * 4;
#pragma unroll
            for (int r = 0; r < 4; ++r) {
                float v = acc[i][j][r];
                if (gm + r >= rstar) m1 = fmaxf(m1, v); else m0 = fmaxf(m0, v);
            }
        }
        m0 = fmaxf(m0, __shfl_xor(m0, 16)); m0 = fmaxf(m0, __shfl_xor(m0, 32));
        m1 = fmaxf(m1, __shfl_xor(m1, 16)); m1 = fmaxf(m1, __shfl_xor(m1, 32));
        if (lane < 16) {
            maxw[w][0][16 * j + lane] = m0;
            maxw[w][1][16 * j + lane] = m1;
        }
    }
    __syncthreads();
#pragma unroll
    for (int s = 0; s < 2; ++s) {
        float vmax = fmaxf(maxw[0][s][tid], maxw[1][s][tid]);
        part[(size_t)(mtile * 2 + s) * 1024 + nBase + tid] = vmax;
    }
}

// ---------------- fused: imgcls (blocks [0,B_)) + compaction (blocks [B_,B_+49)) ----------------
__global__ __launch_bounds__(256) void post_kernel(
        const float* __restrict__ part, const float* __restrict__ saw,
        float* __restrict__ img, float* __restrict__ cls,
        const float* __restrict__ L, const int* __restrict__ labels,
        int* __restrict__ cnt, int* __restrict__ idxList, float* __restrict__ EList) {
    __shared__ float simg[CK_];
    if (blockIdx.x < B_) {
        int b = blockIdx.x;
        int t0 = (196 * b) >> 7;
        int t1 = (196 * b + 195) >> 7;
        for (int n = threadIdx.x; n < CK_; n += 256) {
            float m = -INFINITY;
            for (int t = t0; t <= t1; ++t) {
                int iA = (t << 7) / 196;
                int s = (iA == b) ? 0 : 1;
                m = fmaxf(m, part[(size_t)(t * 2 + s) * 1024 + n]);
            }
            img[b * CK_ + n] = m;
            simg[n] = m;
        }
        __syncthreads();
        int c = threadIdx.x;
        if (c < NCLS) {
            float w[K_];
            float mx = -INFINITY;
#pragma unroll
            for (int k = 0; k < K_; ++k) { w[k] = saw[c * K_ + k]; mx = fmaxf(mx, w[k]); }
            float ssum = 0.f;
#pragma unroll
            for (int k = 0; k < K_; ++k) { w[k] = expf(w[k] - mx); ssum += w[k]; }
            float acc = 0.f;
#pragma unroll
            for (int k = 0; k < K_; ++k)
                acc += simg[c * K_ + k] * (w[k] / ssum * (float)K_);
            cls[b * NCLS + c] = acc * INV_TEMP;
        }
    } else {
        int n = (blockIdx.x - B_) * 256 + threadIdx.x;
        if (n >= N_) return;
        int c = labels[n];
        int slot = atomicAdd(&cnt[c], 1);
        if (slot < CAP2) {
            idxList[c * CAP2 + slot] = n;
            const float* lp = L + (size_t)n * CK_ + c * K_;
#pragma unroll
            for (int k = 0; k < K_; ++k)
                EList[((size_t)(c * K_ + k)) * CAP2 + slot] = expf(lp[k] * INV_EPS);
        }
    }
}

// ---------------- fused sinkhorn + EMA: one block per class, W stays in LDS ----------------
#define NJ (CAP2/64)
__global__ __launch_bounds__(256) void sinkema_kernel(
    const int* __restrict__ cnt, const int* __restrict__ idxList,
    const float* __restrict__ EList, const float* __restrict__ invR,
    const float* __restrict__ rawP, const float* __restrict__ proto,
    float* __restrict__ outAssign, float* __restrict__ outProto) {
    int c = blockIdx.x;
    int tid = threadIdx.x;
    int Nc = cnt[c]; if (Nc > CAP2) Nc = CAP2;
    size_t protoOff = (size_t)c * K_ * D_;
    if (Nc == 0) {  // absent class: copy prototypes through
        for (int i = tid; i < K_ * D_; i += 256)
            outProto[protoOff + i] = proto[protoOff + i];
        return;
    }
    __shared__ float s_w[K_][CAP2];
    __shared__ int s_idx[CAP2];
    for (int i = tid; i < CAP2; i += 256)
        s_idx[i] = (i < Nc) ? idxList[c * CAP2 + i] : 0;

    if (tid < 64) {   // wave 0: sinkhorn for this class
        int lane = tid;
        float e[NJ][K_];
        float cn[NJ];
#pragma unroll
        for (int j = 0; j < NJ; ++j) {
            int n = j * 64 + lane;
            bool v = n < Nc;
            cn[j] = v ? 1.f : 0.f;
#pragma unroll
            for (int k = 0; k < K_; ++k)
                e[j][k] = v ? EList[((size_t)(c * K_ + k)) * CAP2 + n] : 0.f;
        }
        float r[K_];
        for (int it = 0; it < 3; ++it) {
#pragma unroll
            for (int k = 0; k < K_; ++k) {
                float s = 0.f;
#pragma unroll
                for (int j = 0; j < NJ; ++j) s += e[j][k] * cn[j];
                for (int o = 32; o > 0; o >>= 1) s += __shfl_xor(s, o, 64);
                r[k] = 1.f / ((float)K_ * s);
            }
#pragma unroll
            for (int j = 0; j < NJ; ++j) {
                float t = 0.f;
#pragma unroll
                for (int k = 0; k < K_; ++k) t += e[j][k] * r[k];
                cn[j] = (j * 64 + lane < Nc) ? 1.f / ((float)Nc * t) : 0.f;
            }
        }
#pragma unroll
        for (int j = 0; j < NJ; ++j) {
            int n = j * 64 + lane;
            if (n >= Nc) continue;
            int idxn = idxList[c * CAP2 + n];
            int kb = 0; float best = e[j][0] * r[0];
#pragma unroll
            for (int k = 1; k < K_; ++k) {
                float v = e[j][k] * r[k];
                if (v > best) { best = v; kb = k; }
            }
            outAssign[idxn] = (float)(kb + c * K_);
            float scale = cn[j] * (float)Nc * (1.0f - GAMMA_) * invR[idxn];
#pragma unroll
            for (int k = 0; k < K_; ++k)
                s_w[k][n] = e[j][k] * r[k] * scale;
        }
    }
    __syncthreads();

    // EMA: all 256 threads; each owns d = tid, tid+256, tid+512
    float a0[K_] = {}, a1[K_] = {}, a2[K_] = {};
    for (int n = 0; n < Nc; ++n) {
        const float* rp = rawP + (size_t)s_idx[n] * D_;
        float v0 = rp[tid], v1 = rp[tid + 256], v2 = rp[tid + 512];
#pragma unroll
        for (int k = 0; k < K_; ++k) {
            float wv = s_w[k][n];
            a0[k] = fmaf(wv, v0, a0[k]);
            a1[k] = fmaf(wv, v1, a1[k]);
            a2[k] = fmaf(wv, v2, a2[k]);
        }
    }
#pragma unroll
    for (int k = 0; k < K_; ++k) {
        size_t o = protoOff + (size_t)k * D_;
        outProto[o + tid]       = fmaf(GAMMA_, proto[o + tid],       a0[k]);
        outProto[o + tid + 256] = fmaf(GAMMA_, proto[o + tid + 256], a1[k]);
        outProto[o + tid + 512] = fmaf(GAMMA_, proto[o + tid + 512], a2[k]);
    }
}

extern "C" void kernel_launch(void* const* d_in, const int* in_sizes, int n_in,
                              void* d_out, int out_size, void* d_ws, size_t ws_size,
                              hipStream_t stream) {
    (void)in_sizes; (void)n_in; (void)out_size; (void)ws_size;
    const float* patch  = (const float*)d_in[0];
    const float* rawp   = (const float*)d_in[1];
    const float* proto  = (const float*)d_in[2];
    const float* saw    = (const float*)d_in[3];
    const int*   labels = (const int*)d_in[4];

    float* out    = (float*)d_out;
    float* logits = out;
    float* img    = out + 12606720;
    float* cls    = out + 12671040;
    float* assign = out + 12683840;
    float* pnew   = out + 12696384;

    float* ws   = (float*)d_ws;
    float* invR = ws;                                      // N_
    unsigned short* Abf = (unsigned short*)(ws + N_);      // N_*768 bf16 (pre-normalized)
    unsigned short* Bbf = Abf + (size_t)N_ * D_;           // NPAD*768 bf16 (pre-normalized)
    int*   cnt     = (int*)(Bbf + (size_t)NPAD * D_);      // 256
    int*   idxList = cnt + 256;                            // C_*CAP2
    float* EList   = (float*)(idxList + C_ * CAP2);        // C_*K_*CAP2
    float* WList   = EList + (size_t)C_ * K_ * CAP2;       // (unused; keeps layout)
    float* part    = WList + (size_t)C_ * K_ * CAP2;       // MTILES*2*1024

    norm_all_kernel<<<ROWS_TOT / 4, 256, 0, stream>>>(patch, rawp, proto, invR, Abf, Bbf, cnt);
    gemm_mfma_kernel<<<dim3(NPAD / BN, MTILES), 128, 0, stream>>>(Abf, Bbf, logits, part);
    post_kernel<<<B_ + N_ / 256, 256, 0, stream>>>(part, saw, img, cls, logits, labels,
                                                   cnt, idxList, EList);
    sinkema_kernel<<<C_, 256, 0, stream>>>(cnt, idxList, EList, invR, rawp, proto,
                                           assign, pnew);
}

// Round 4
// 189.541 us; speedup vs baseline: 1.0787x; 1.0787x over previous
//
#include <hip/hip_runtime.h>
#include <math.h>

#define B_ 64
#define P_ 196
#define D_ 768
#define C_ 201
#define K_ 5
#define N_ (B_*P_)      // 12544
#define CK_ (C_*K_)     // 1005
#define NPAD 1024
#define NCLS 200
#define GAMMA_ 0.999f
#define INV_TEMP 5.0f
#define INV_EPS 20.0f
#define CAP2 256
#define EPAD 8          // padded floats per (c,slot) in EList
#define MTILES 98       // 12544/128
#define ROWS_TOT (2*N_ + NPAD)   // 26112 rows for the norm pass

typedef short s16x8 __attribute__((ext_vector_type(8)));
typedef float f32x4 __attribute__((ext_vector_type(4)));
typedef unsigned short u16x4 __attribute__((ext_vector_type(4)));

typedef __attribute__((address_space(3))) void lds_void;
typedef __attribute__((address_space(1))) const void g_void;
#define GLD16(gp, lp) __builtin_amdgcn_global_load_lds((g_void*)(gp), (lds_void*)(lp), 16, 0, 0)

__device__ __forceinline__ unsigned short f2bf(float f) {
    unsigned int u = __float_as_uint(f);
    unsigned int r = (u + 0x7FFFu + ((u >> 16) & 1u)) >> 16;
    return (unsigned short)r;
}

// ---------------- norms + pre-scaled bf16 conversion: ONE WAVE PER ROW ----------------
__global__ __launch_bounds__(256) void norm_all_kernel(
        const float* __restrict__ patch, const float* __restrict__ rawp,
        const float* __restrict__ proto, float* __restrict__ invR,
        unsigned short* __restrict__ Abf, unsigned short* __restrict__ Bbf,
        int* __restrict__ cnt) {
    if (blockIdx.x == 0 && threadIdx.x < C_) cnt[threadIdx.x] = 0;
    int gw = blockIdx.x * 4 + (threadIdx.x >> 6);   // row index
    int lane = threadIdx.x & 63;
    const float* src; unsigned short* dst; int realR; int r; bool wantInv = false;
    if (gw < N_) { r = gw; src = patch; dst = Abf; realR = N_; }
    else if (gw < 2 * N_) { r = gw - N_; src = rawp; dst = nullptr; realR = N_; wantInv = true; }
    else { r = gw - 2 * N_; src = proto; dst = Bbf; realR = CK_; }
    unsigned short* brow = dst ? dst + (size_t)r * D_ : nullptr;
    if (r >= realR) {  // zero-pad proto rows
        u16x4 z = (u16x4)0;
        *(u16x4*)(brow + lane * 4)       = z;
        *(u16x4*)(brow + lane * 4 + 256) = z;
        *(u16x4*)(brow + lane * 4 + 512) = z;
        return;
    }
    const float4* row4 = (const float4*)(src + (size_t)r * D_);
    float4 v0 = row4[lane], v1 = row4[lane + 64], v2 = row4[lane + 128];
    float s = v0.x*v0.x + v0.y*v0.y + v0.z*v0.z + v0.w*v0.w
            + v1.x*v1.x + v1.y*v1.y + v1.z*v1.z + v1.w*v1.w
            + v2.x*v2.x + v2.y*v2.y + v2.z*v2.z + v2.w*v2.w;
#pragma unroll
    for (int o = 1; o < 64; o <<= 1) s += __shfl_xor(s, o, 64);
    float sc = 1.f / fmaxf(sqrtf(s), 1e-12f);
    if (brow) {
        u16x4 p0 = { f2bf(v0.x*sc), f2bf(v0.y*sc), f2bf(v0.z*sc), f2bf(v0.w*sc) };
        u16x4 p1 = { f2bf(v1.x*sc), f2bf(v1.y*sc), f2bf(v1.z*sc), f2bf(v1.w*sc) };
        u16x4 p2 = { f2bf(v2.x*sc), f2bf(v2.y*sc), f2bf(v2.z*sc), f2bf(v2.w*sc) };
        *(u16x4*)(brow + lane * 4)       = p0;
        *(u16x4*)(brow + lane * 4 + 256) = p1;
        *(u16x4*)(brow + lane * 4 + 512) = p2;
    } else if (wantInv && lane == 0) invR[r] = sc;
}

// ---------------- bf16 MFMA GEMM + fused per-tile image max (exact R6 config: 48us) ----------------
#define BM 128
#define BN 128
#define BKq 32
#define KITER (D_/BKq)   // 24
#define NBUF 3
__global__ __launch_bounds__(256) void gemm_mfma_kernel(
    const unsigned short* __restrict__ Ab, const unsigned short* __restrict__ Bb,
    float* __restrict__ Cc,                 // logits [N_][CK_]
    float* __restrict__ part) {             // [MTILES][2][1024] per-(tile,slot) col max
    __shared__ short As[NBUF][BM * BKq];
    __shared__ short Bs[NBUF][BN * BKq];
    __shared__ float maxw[4][2][BN];
    int tid = threadIdx.x;
    // XCD-aware chunked swizzle (bijective: 784 = 8*98)
    int bid = blockIdx.y * 8 + blockIdx.x;
    int swz = (bid & 7) * MTILES + (bid >> 3);
    int mtile = swz >> 3;
    int ntile = swz & 7;
    int mBase = mtile * BM;
    int nBase = ntile * BN;
    int w = tid >> 6;
    int lane = tid & 63;
    int wm = (w >> 1) * 64;
    int wn = (w & 1) * 64;
    int mrow = lane & 15;
    int kq = (lane >> 4) * 8;

    f32x4 acc[4][4];
#pragma unroll
    for (int i = 0; i < 4; ++i)
#pragma unroll
        for (int j = 0; j < 4; ++j) acc[i][j] = (f32x4)(0.f);

    int c0 = tid, c1 = tid + 256;
    const unsigned short* ga0 = Ab + (size_t)(mBase + (c0 >> 2)) * D_ + (c0 & 3) * 8;
    const unsigned short* ga1 = Ab + (size_t)(mBase + (c1 >> 2)) * D_ + (c1 & 3) * 8;
    const unsigned short* gb0 = Bb + (size_t)(nBase + (c0 >> 2)) * D_ + (c0 & 3) * 8;
    const unsigned short* gb1 = Bb + (size_t)(nBase + (c1 >> 2)) * D_ + (c1 & 3) * 8;

    auto stage = [&](int buf, int k0) {
        GLD16(ga0 + k0, &As[buf][c0 * 8]);
        GLD16(ga1 + k0, &As[buf][c1 * 8]);
        GLD16(gb0 + k0, &Bs[buf][c0 * 8]);
        GLD16(gb1 + k0, &Bs[buf][c1 * 8]);
    };

    stage(0, 0);
    stage(1, BKq);
    for (int u = 0; u < KITER; ++u) {
        if (u < KITER - 1) asm volatile("s_waitcnt vmcnt(4)" ::: "memory");
        else               asm volatile("s_waitcnt vmcnt(0)" ::: "memory");
        __builtin_amdgcn_s_barrier();
        __builtin_amdgcn_sched_barrier(0);
        if (u + 2 < KITER) stage((u + 2) % NBUF, (u + 2) * BKq);
        const short* Ac = As[u % NBUF];
        const short* Bc = Bs[u % NBUF];
        s16x8 a[4], b[4];
#pragma unroll
        for (int i = 0; i < 4; ++i)
            a[i] = *(const s16x8*)&Ac[(wm + 16 * i + mrow) * BKq + kq];
#pragma unroll
        for (int j = 0; j < 4; ++j)
            b[j] = *(const s16x8*)&Bc[(wn + 16 * j + mrow) * BKq + kq];
#pragma unroll
        for (int i = 0; i < 4; ++i)
#pragma unroll
            for (int j = 0; j < 4; ++j)
                acc[i][j] = __builtin_amdgcn_mfma_f32_16x16x32_bf16(a[i], b[j], acc[i][j], 0, 0, 0);
    }

    // epilogue: plain stores (NT stores measured worse: WRITE_SIZE 55->96MB)
#pragma unroll
    for (int i = 0; i < 4; ++i) {
        int gm = mBase + wm + 16 * i + (lane >> 4) * 4;
#pragma unroll
        for (int j = 0; j < 4; ++j) {
            int gn = nBase + wn + 16 * j + (lane & 15);
            if (gn < CK_) {
                Cc[(size_t)(gm + 0) * CK_ + gn] = acc[i][j][0];
                Cc[(size_t)(gm + 1) * CK_ + gn] = acc[i][j][1];
                Cc[(size_t)(gm + 2) * CK_ + gn] = acc[i][j][2];
                Cc[(size_t)(gm + 3) * CK_ + gn] = acc[i][j][3];
            }
        }
    }

    // fused max over this tile's rows, split by image boundary (tile spans <=2 images)
    int imgA = mBase / 196;
    int rstar = 196 * (imgA + 1);
#pragma unroll
    for (int j = 0; j < 4; ++j) {
        float m0 = -INFINITY, m1 = -INFINITY;
#pragma unroll
        for (int i = 0; i < 4; ++i) {
            int gm = mBase + wm + 16 * i + (lane >> 4) * 4;
#pragma unroll
            for (int r = 0; r < 4; ++r) {
                float v = acc[i][j][r];
                if (gm + r >= rstar) m1 = fmaxf(m1, v); else m0 = fmaxf(m0, v);
            }
        }
        m0 = fmaxf(m0, __shfl_xor(m0, 16)); m0 = fmaxf(m0, __shfl_xor(m0, 32));
        m1 = fmaxf(m1, __shfl_xor(m1, 16)); m1 = fmaxf(m1, __shfl_xor(m1, 32));
        if (lane < 16) {
            maxw[w][0][wn + 16 * j + lane] = m0;
            maxw[w][1][wn + 16 * j + lane] = m1;
        }
    }
    __syncthreads();
    int s = tid >> 7, col = tid & 127, h = col >> 6;
    float vmax = fmaxf(maxw[h][s][col], maxw[h + 2][s][col]);
    part[(size_t)(mtile * 2 + s) * 1024 + nBase + col] = vmax;
}

// ---------------- fused: imgcls (blocks [0,B_)) + compaction (blocks [B_,B_+49)) ----------------
// R8: EList layout -> [c][slot][EPAD]: contiguous float4+float per thread (was stride-1KB scatter)
__global__ __launch_bounds__(256) void post_kernel(
        const float* __restrict__ part, const float* __restrict__ saw,
        float* __restrict__ img, float* __restrict__ cls,
        const float* __restrict__ L, const int* __restrict__ labels,
        int* __restrict__ cnt, int* __restrict__ idxList, float* __restrict__ EList) {
    __shared__ float simg[CK_];
    if (blockIdx.x < B_) {
        int b = blockIdx.x;
        int t0 = (196 * b) >> 7;
        int t1 = (196 * b + 195) >> 7;
        for (int n = threadIdx.x; n < CK_; n += 256) {
            float m = -INFINITY;
            for (int t = t0; t <= t1; ++t) {
                int iA = (t << 7) / 196;
                int s = (iA == b) ? 0 : 1;
                m = fmaxf(m, part[(size_t)(t * 2 + s) * 1024 + n]);
            }
            img[b * CK_ + n] = m;
            simg[n] = m;
        }
        __syncthreads();
        int c = threadIdx.x;
        if (c < NCLS) {
            float w[K_];
            float mx = -INFINITY;
#pragma unroll
            for (int k = 0; k < K_; ++k) { w[k] = saw[c * K_ + k]; mx = fmaxf(mx, w[k]); }
            float ssum = 0.f;
#pragma unroll
            for (int k = 0; k < K_; ++k) { w[k] = expf(w[k] - mx); ssum += w[k]; }
            float acc = 0.f;
#pragma unroll
            for (int k = 0; k < K_; ++k)
                acc += simg[c * K_ + k] * (w[k] / ssum * (float)K_);
            cls[b * NCLS + c] = acc * INV_TEMP;
        }
    } else {
        int n = (blockIdx.x - B_) * 256 + threadIdx.x;
        if (n >= N_) return;
        int c = labels[n];
        int slot = atomicAdd(&cnt[c], 1);
        if (slot < CAP2) {
            idxList[c * CAP2 + slot] = n;
            const float* lp = L + (size_t)n * CK_ + c * K_;
            float e0 = expf(lp[0] * INV_EPS), e1 = expf(lp[1] * INV_EPS);
            float e2 = expf(lp[2] * INV_EPS), e3 = expf(lp[3] * INV_EPS);
            float e4 = expf(lp[4] * INV_EPS);
            float* ep = EList + ((size_t)c * CAP2 + slot) * EPAD;
            float4 v4 = { e0, e1, e2, e3 };
            *(float4*)ep = v4;
            ep[4] = e4;
        }
    }
}

// ---------------- fused sinkhorn + EMA: one block per class, 768 threads (12 waves) ----------------
// R8: was 256 thr (0.78 blocks/CU, 4 waves -> gather-latency-bound). Now each thread owns
// exactly one d of 768: per-n body = 1 coalesced row-load + 5 FMA, 12 waves hide latency.
#define NJ (CAP2/64)
__global__ __launch_bounds__(768) void sinkema_kernel(
    const int* __restrict__ cnt, const int* __restrict__ idxList,
    const float* __restrict__ EList, const float* __restrict__ invR,
    const float* __restrict__ rawP, const float* __restrict__ proto,
    float* __restrict__ outAssign, float* __restrict__ outProto) {
    int c = blockIdx.x;
    int tid = threadIdx.x;
    int Nc = cnt[c]; if (Nc > CAP2) Nc = CAP2;
    size_t protoOff = (size_t)c * K_ * D_;
    if (Nc == 0) {  // absent class: copy prototypes through
        for (int i = tid; i < K_ * D_; i += 768)
            outProto[protoOff + i] = proto[protoOff + i];
        return;
    }
    __shared__ float s_w[K_][CAP2];
    __shared__ int s_idx[CAP2];
    for (int i = tid; i < CAP2; i += 768)
        s_idx[i] = (i < Nc) ? idxList[c * CAP2 + i] : 0;

    if (tid < 64) {   // wave 0: sinkhorn for this class
        int lane = tid;
        float e[NJ][K_];
        float cn[NJ];
#pragma unroll
        for (int j = 0; j < NJ; ++j) {
            int n = j * 64 + lane;
            bool v = n < Nc;
            cn[j] = v ? 1.f : 0.f;
            const float* ep = EList + ((size_t)c * CAP2 + n) * EPAD;
            float4 v4 = v ? *(const float4*)ep : make_float4(0.f, 0.f, 0.f, 0.f);
            e[j][0] = v4.x; e[j][1] = v4.y; e[j][2] = v4.z; e[j][3] = v4.w;
            e[j][4] = v ? ep[4] : 0.f;
        }
        float r[K_];
        for (int it = 0; it < 3; ++it) {
#pragma unroll
            for (int k = 0; k < K_; ++k) {
                float s = 0.f;
#pragma unroll
                for (int j = 0; j < NJ; ++j) s += e[j][k] * cn[j];
                for (int o = 32; o > 0; o >>= 1) s += __shfl_xor(s, o, 64);
                r[k] = 1.f / ((float)K_ * s);
            }
#pragma unroll
            for (int j = 0; j < NJ; ++j) {
                float t = 0.f;
#pragma unroll
                for (int k = 0; k < K_; ++k) t += e[j][k] * r[k];
                cn[j] = (j * 64 + lane < Nc) ? 1.f / ((float)Nc * t) : 0.f;
            }
        }
#pragma unroll
        for (int j = 0; j < NJ; ++j) {
            int n = j * 64 + lane;
            if (n >= Nc) continue;
            int idxn = s_idx[n];
            int kb = 0; float best = e[j][0] * r[0];
#pragma unroll
            for (int k = 1; k < K_; ++k) {
                float v = e[j][k] * r[k];
                if (v > best) { best = v; kb = k; }
            }
            outAssign[idxn] = (float)(kb + c * K_);
            float scale = cn[j] * (float)Nc * (1.0f - GAMMA_) * invR[idxn];
#pragma unroll
            for (int k = 0; k < K_; ++k)
                s_w[k][n] = e[j][k] * r[k] * scale;
        }
    }
    __syncthreads();

    // EMA: 768 threads, thread owns d = tid; unroll-4 keeps 4 gathered rows in flight
    float acc[K_] = {};
    int n = 0;
    for (; n + 3 < Nc; n += 4) {
        float v0 = rawP[(size_t)s_idx[n]     * D_ + tid];
        float v1 = rawP[(size_t)s_idx[n + 1] * D_ + tid];
        float v2 = rawP[(size_t)s_idx[n + 2] * D_ + tid];
        float v3 = rawP[(size_t)s_idx[n + 3] * D_ + tid];
#pragma unroll
        for (int k = 0; k < K_; ++k) {
            acc[k] = fmaf(s_w[k][n],     v0, acc[k]);
            acc[k] = fmaf(s_w[k][n + 1], v1, acc[k]);
            acc[k] = fmaf(s_w[k][n + 2], v2, acc[k]);
            acc[k] = fmaf(s_w[k][n + 3], v3, acc[k]);
        }
    }
    for (; n < Nc; ++n) {
        float v0 = rawP[(size_t)s_idx[n] * D_ + tid];
#pragma unroll
        for (int k = 0; k < K_; ++k) acc[k] = fmaf(s_w[k][n], v0, acc[k]);
    }
#pragma unroll
    for (int k = 0; k < K_; ++k) {
        size_t o = protoOff + (size_t)k * D_ + tid;
        outProto[o] = fmaf(GAMMA_, proto[o], acc[k]);
    }
}

extern "C" void kernel_launch(void* const* d_in, const int* in_sizes, int n_in,
                              void* d_out, int out_size, void* d_ws, size_t ws_size,
                              hipStream_t stream) {
    (void)in_sizes; (void)n_in; (void)out_size; (void)ws_size;
    const float* patch  = (const float*)d_in[0];
    const float* rawp   = (const float*)d_in[1];
    const float* proto  = (const float*)d_in[2];
    const float* saw    = (const float*)d_in[3];
    const int*   labels = (const int*)d_in[4];

    float* out    = (float*)d_out;
    float* logits = out;
    float* img    = out + 12606720;
    float* cls    = out + 12671040;
    float* assign = out + 12683840;
    float* pnew   = out + 12696384;

    float* ws   = (float*)d_ws;
    float* invR = ws;                                      // N_
    unsigned short* Abf = (unsigned short*)(ws + N_);      // N_*768 bf16 (pre-normalized)
    unsigned short* Bbf = Abf + (size_t)N_ * D_;           // NPAD*768 bf16 (pre-normalized)
    int*   cnt     = (int*)(Bbf + (size_t)NPAD * D_);      // 256
    int*   idxList = cnt + 256;                            // C_*CAP2
    float* EList   = (float*)(idxList + C_ * CAP2);        // C_*CAP2*EPAD (411648 < old 514560 span)
    float* part    = EList + (size_t)2 * C_ * K_ * CAP2;   // MTILES*2*1024 (offset unchanged)

    norm_all_kernel<<<ROWS_TOT / 4, 256, 0, stream>>>(patch, rawp, proto, invR, Abf, Bbf, cnt);
    gemm_mfma_kernel<<<dim3(NPAD / BN, MTILES), 256, 0, stream>>>(Abf, Bbf, logits, part);
    post_kernel<<<B_ + N_ / 256, 256, 0, stream>>>(part, saw, img, cls, logits, labels,
                                                   cnt, idxList, EList);
    sinkema_kernel<<<C_, 768, 0, stream>>>(cnt, idxList, EList, invR, rawp, proto,
                                           assign, pnew);
}